// Round 6
// baseline (150.735 us; speedup 1.0000x reference)
//
#include <hip/hip_runtime.h>
#include <hip/hip_bf16.h>

// GAT layer, B=8 N=1024 IN=128 H=4 D=32. Inputs f32, OUTPUT f32.
//
// k1      : h = x@W^T (W bf16 in LDS, 16 rows/block, 4 acc/thread);
//           s/t/e1/e2 per (row,head), transposed [h][bn].
// k_rank  : rank sort by t per (b,h) via brute-force u64-key ranking
//           (key = orderable(t)<<32 | idx -> strict total order, no ties),
//           scatter t/idx/e1/e2 into sorted order in ws.
// k_scan  : per (b,h): chunk sums of e1*h (suffix) / e2*h (prefix) + denoms,
//           WAVE-PARALLEL shuffle scans over 64 chunks, tables -> ws.
// k_comb  : per query: binary search split p (t_k >= -s_q is a sorted suffix),
//           out = (A*suf1[p] + B*pre2[p]) / (A*d1[p] + B*d2[p]) with <=16-key
//           boundary partials per side.

#define B_   8
#define N_   1024
#define BN   (B_ * N_)
#define IND  128
#define H_   4
#define D_   32
#define NEG  0.2f
#define CH   16
#define NCH  (N_ / CH)       // 64
#define QB   64              // queries per k_comb block
#define RT   16              // rows per k1 block

typedef float float4_ __attribute__((ext_vector_type(4)));

__device__ __forceinline__ float bf2f(ushort u) {
    union { unsigned int i; float f; } v; v.i = ((unsigned int)u) << 16; return v.f;
}
__device__ __forceinline__ ushort f2bf(float f) {
    union { float f; unsigned int i; } v; v.f = f;
    unsigned int lsb = (v.i >> 16) & 1u;
    v.i += 0x7fffu + lsb;
    return (ushort)(v.i >> 16);
}

// ---------------- Kernel 1: h = x@W^T, alphas, exp factors ----------------
// grid = BN/RT blocks, 512 threads: 4 row-groups x 128 cols; 4 rows/thread.
__global__ __launch_bounds__(512) void k_h_alpha(
    const float* __restrict__ x,      // [B*N,128]
    const float* __restrict__ alive,  // [B*N]
    const float* __restrict__ W,      // [128,128]
    const float* __restrict__ a_src,  // [128]
    const float* __restrict__ a_dst,  // [128]
    float* __restrict__ h_ws,         // [B*N,128]
    float* __restrict__ sT,           // [H][BN]
    float* __restrict__ tT,           // [H][BN]
    float* __restrict__ e1T,          // [H][BN]
    float* __restrict__ e2T)          // [H][BN]
{
    __shared__ float  xs[RT][IND];    // 8 KB
    __shared__ ushort Wl[IND][132];   // 33 KB; 132 ushorts = 66 words (stride 66: banks spread)
    __shared__ float  asrc[IND], adst[IND];

    const int t     = threadIdx.x;
    const int c     = t & 127;        // col (wave-uniform row-group, consecutive c)
    const int rg    = t >> 7;         // 0..3
    const int rbase = blockIdx.x * RT;

    {   // stage x: 16 rows x 128 = 512 float4, 1 per thread
        int row = t >> 5, c4 = (t & 31) * 4;
        *reinterpret_cast<float4_*>(&xs[row][c4]) =
            *reinterpret_cast<const float4_*>(&x[(size_t)(rbase + row) * IND + c4]);
    }
    if (t < IND) { asrc[t] = a_src[t]; adst[t] = a_dst[t]; }

    const float2* Wf2 = reinterpret_cast<const float2*>(W);
    #pragma unroll
    for (int i = t; i < 8192; i += 512) {
        float2 w2 = Wf2[i];
        unsigned int u = ((unsigned int)f2bf(w2.y) << 16) | (unsigned int)f2bf(w2.x);
        reinterpret_cast<unsigned int*>(Wl[i >> 6])[i & 63] = u;
    }
    __syncthreads();

    const uint2* wrow2 = reinterpret_cast<const uint2*>(Wl[c]);  // 264B rows: 8B aligned
    float acc[4] = {0.f, 0.f, 0.f, 0.f};
    #pragma unroll
    for (int j = 0; j < 32; ++j) {        // 4 k per iter
        uint2 u2 = wrow2[j];
        float w0 = bf2f((ushort)(u2.x & 0xffffu));
        float w1 = bf2f((ushort)(u2.x >> 16));
        float w2 = bf2f((ushort)(u2.y & 0xffffu));
        float w3 = bf2f((ushort)(u2.y >> 16));
        #pragma unroll
        for (int i = 0; i < 4; ++i) {
            const float4_ xv = *reinterpret_cast<const float4_*>(&xs[rg * 4 + i][j * 4]);
            acc[i] = fmaf(xv[0], w0, acc[i]);
            acc[i] = fmaf(xv[1], w1, acc[i]);
            acc[i] = fmaf(xv[2], w2, acc[i]);
            acc[i] = fmaf(xv[3], w3, acc[i]);
        }
    }

    const int head = c >> 5;
    #pragma unroll
    for (int i = 0; i < 4; ++i) {
        const int row = rbase + rg * 4 + i;
        h_ws[(size_t)row * IND + c] = acc[i];
        float ps = acc[i] * asrc[c];
        float pt = acc[i] * adst[c];
        #pragma unroll
        for (int m = 16; m >= 1; m >>= 1) {
            ps += __shfl_xor(ps, m);
            pt += __shfl_xor(pt, m);
        }
        if ((t & 31) == 0) {
            int idx = head * BN + row;
            sT[idx] = ps;
            tT[idx] = pt;
            float am = (alive[row] >= 0.5f) ? 1.f : 0.f;
            e1T[idx] = am * __expf(pt);
            e2T[idx] = am * __expf(NEG * pt);
        }
    }
}

// ---------------- Kernel 2: brute-force u64 rank + scatter ----------------
// grid = (4, H, B), 256 threads. Thread owns key i0 = chunk*256+tid.
__global__ __launch_bounds__(256) void k_rank(
    const float* __restrict__ tT,
    const float* __restrict__ e1T,
    const float* __restrict__ e2T,
    float* __restrict__ tSg,   // [32][N]
    int*   __restrict__ kIg,
    float* __restrict__ e1g,
    float* __restrict__ e2g)
{
    __shared__ unsigned long long keys[N_];   // 8 KB
    const int h = blockIdx.y, b = blockIdx.z;
    const int base = h * BN + b * N_;
    for (int i = threadIdx.x; i < N_; i += 256) {
        unsigned int u = __float_as_uint(tT[base + i]);
        u = (u & 0x80000000u) ? ~u : (u | 0x80000000u);   // orderable transform
        keys[i] = ((unsigned long long)u << 32) | (unsigned int)i;
    }
    __syncthreads();

    const int i0 = blockIdx.x * 256 + threadIdx.x;
    const unsigned long long mk = keys[i0];
    int rank = 0;
    const ulonglong2* k2p = reinterpret_cast<const ulonglong2*>(keys);
    #pragma unroll 8
    for (int j = 0; j < N_ / 2; ++j) {
        ulonglong2 kk = k2p[j];
        rank += (int)(kk.x < mk) + (int)(kk.y < mk);
    }
    const int o = (b * H_ + h) * N_ + rank;
    tSg[o] = tT[base + i0];
    kIg[o] = i0;
    e1g[o] = e1T[base + i0];
    e2g[o] = e2T[base + i0];
}

// ---------------- Kernel 3: chunk sums + wave-parallel scans --------------
// grid = (H, B), 256 threads.
__global__ __launch_bounds__(256) void k_scan(
    const float* __restrict__ h_ws,
    const int*   __restrict__ kIg,
    const float* __restrict__ e1g,
    const float* __restrict__ e2g,
    float* __restrict__ pre2g,   // [32][65][32]
    float* __restrict__ suf1g,   // [32][66][32]
    float* __restrict__ dpre2g,  // [32][65]
    float* __restrict__ dsuf1g)  // [32][66]
{
    __shared__ int   kI[N_];
    __shared__ float e1S[N_], e2S[N_];
    __shared__ float pre2[NCH + 1][33];   // pad 33: scan reads hit distinct banks
    __shared__ float suf1[NCH + 2][33];
    __shared__ float dpre2[NCH + 1], dsuf1[NCH + 2];

    const int h = blockIdx.x, b = blockIdx.y;
    const int bhi = b * H_ + h;
    const int so  = bhi * N_;
    const int tid = threadIdx.x;

    for (int i = tid; i < N_; i += 256) {
        kI[i]  = kIg[so + i];
        e1S[i] = e1g[so + i];
        e2S[i] = e2g[so + i];
    }
    __syncthreads();

    // chunk sums; (cc, dim-group) cells; 8 dg lanes share each key row -> coalesced
    for (int c4 = tid; c4 < NCH * 8; c4 += 256) {
        int cc = c4 >> 3, dg = c4 & 7;
        float4_ a1 = {0.f, 0.f, 0.f, 0.f}, a2 = {0.f, 0.f, 0.f, 0.f};
        #pragma unroll
        for (int jj = 0; jj < CH; ++jj) {
            int j = cc * CH + jj;
            const float4_ hv = *reinterpret_cast<const float4_*>(
                &h_ws[(size_t)(b * N_ + kI[j]) * IND + h * D_ + dg * 4]);
            a1 += e1S[j] * hv;
            a2 += e2S[j] * hv;
        }
        #pragma unroll
        for (int u = 0; u < 4; ++u) {
            pre2[cc + 1][dg * 4 + u] = a2[u];
            suf1[cc][dg * 4 + u]     = a1[u];
        }
    }
    if (tid < NCH) {
        float s = 0.f;
        #pragma unroll
        for (int jj = 0; jj < CH; ++jj) s += e2S[tid * CH + jj];
        dpre2[tid + 1] = s;
    } else if (tid < 2 * NCH) {
        int cc = tid - NCH;
        float s = 0.f;
        #pragma unroll
        for (int jj = 0; jj < CH; ++jj) s += e1S[cc * CH + jj];
        dsuf1[cc] = s;
    }
    __syncthreads();

    // wave-parallel scans: wave wv handles dims wv, wv+4, ... (64 chunks = 64 lanes)
    const int wv = tid >> 6, lane = tid & 63;
    for (int d = wv; d < D_; d += 4) {
        float v = pre2[lane + 1][d];
        #pragma unroll
        for (int off = 1; off < 64; off <<= 1) {
            float n = __shfl_up(v, off);
            if (lane >= off) v += n;
        }
        pre2[lane + 1][d] = v;
        if (lane == 0) pre2[0][d] = 0.f;
    }
    for (int d = wv; d < D_; d += 4) {
        float v = suf1[lane][d];
        #pragma unroll
        for (int off = 1; off < 64; off <<= 1) {
            float n = __shfl_down(v, off);
            if (lane < 64 - off) v += n;
        }
        suf1[lane][d] = v;
        if (lane == 0) { suf1[NCH][d] = 0.f; suf1[NCH + 1][d] = 0.f; }
    }
    if (tid < 64) {
        float v = dpre2[lane + 1];
        #pragma unroll
        for (int off = 1; off < 64; off <<= 1) {
            float n = __shfl_up(v, off);
            if (lane >= off) v += n;
        }
        dpre2[lane + 1] = v;
        if (lane == 0) dpre2[0] = 0.f;
    } else if (tid < 128) {
        float v = dsuf1[lane];
        #pragma unroll
        for (int off = 1; off < 64; off <<= 1) {
            float n = __shfl_down(v, off);
            if (lane < 64 - off) v += n;
        }
        dsuf1[lane] = v;
        if (lane == 0) { dsuf1[NCH] = 0.f; dsuf1[NCH + 1] = 0.f; }
    }
    __syncthreads();

    for (int i = tid; i < (NCH + 1) * D_; i += 256)
        pre2g[bhi * (NCH + 1) * D_ + i] = pre2[i >> 5][i & 31];
    for (int i = tid; i < (NCH + 2) * D_; i += 256)
        suf1g[bhi * (NCH + 2) * D_ + i] = suf1[i >> 5][i & 31];
    if (tid < NCH + 1) dpre2g[bhi * (NCH + 1) + tid] = dpre2[tid];
    else if (tid < (NCH + 1) + (NCH + 2)) {
        int i = tid - (NCH + 1);
        dsuf1g[bhi * (NCH + 2) + i] = dsuf1[i];
    }
}

// ---------------- Kernel 4: per-query combine -----------------------------
// grid = (N/QB, H, B), 512 threads: 64 queries x 8 dim-groups.
__global__ __launch_bounds__(512) void k_comb(
    const float* __restrict__ h_ws,
    const float* __restrict__ sT,
    const float* __restrict__ tSg,
    const int*   __restrict__ kIg,
    const float* __restrict__ e1g,
    const float* __restrict__ e2g,
    const float* __restrict__ pre2g,
    const float* __restrict__ suf1g,
    const float* __restrict__ dpre2g,
    const float* __restrict__ dsuf1g,
    float* __restrict__ out)
{
    __shared__ float tS[N_];
    __shared__ int   kI[N_];
    __shared__ float e1S[N_], e2S[N_];
    __shared__ float pre2[NCH + 1][36];   // stride 36: float4-aligned + bank spread
    __shared__ float suf1[NCH + 2][36];
    __shared__ float dpre2[NCH + 1], dsuf1[NCH + 2];

    const int h = blockIdx.y, b = blockIdx.z, qb = blockIdx.x;
    const int bhi = b * H_ + h;
    const int so  = bhi * N_;
    const int tid = threadIdx.x;

    for (int i = tid; i < N_; i += 512) {
        tS[i]  = tSg[so + i];
        kI[i]  = kIg[so + i];
        e1S[i] = e1g[so + i];
        e2S[i] = e2g[so + i];
    }
    for (int i = tid; i < (NCH + 1) * D_; i += 512)
        pre2[i >> 5][i & 31] = pre2g[bhi * (NCH + 1) * D_ + i];
    for (int i = tid; i < (NCH + 2) * D_; i += 512)
        suf1[i >> 5][i & 31] = suf1g[bhi * (NCH + 2) * D_ + i];
    if (tid < NCH + 1) dpre2[tid] = dpre2g[bhi * (NCH + 1) + tid];
    else if (tid < (NCH + 1) + (NCH + 2)) {
        int i = tid - (NCH + 1);
        dsuf1[i] = dsuf1g[bhi * (NCH + 2) + i];
    }
    __syncthreads();

    const int ql  = tid >> 3;         // 0..63
    const int sub = tid & 7;          // dim group
    const int q   = qb * QB + ql;

    const float s  = sT[h * BN + b * N_ + q];
    const float A  = __expf(s);
    const float Bv = __expf(NEG * s);
    const float tau = -s;
    int lo = 0, hi = N_;
    #pragma unroll
    for (int it = 0; it < 10; ++it) {
        int mid = (lo + hi) >> 1;
        if (tS[mid] >= tau) hi = mid; else lo = mid + 1;
    }
    const int p  = lo;
    const int cp = p >> 4;

    float4_ acc2 = *reinterpret_cast<const float4_*>(&pre2[cp][sub * 4]);
    float   den2 = dpre2[cp];
    for (int j = cp << 4; j < p; ++j) {
        float w = e2S[j];
        const float4_ hv = *reinterpret_cast<const float4_*>(
            &h_ws[(size_t)(b * N_ + kI[j]) * IND + h * D_ + sub * 4]);
        acc2 += w * hv;
        den2 += w;
    }
    float4_ acc1 = *reinterpret_cast<const float4_*>(&suf1[cp + 1][sub * 4]);
    float   den1 = dsuf1[cp + 1];
    const int je = min((cp << 4) + CH, N_);
    for (int j = p; j < je; ++j) {
        float w = e1S[j];
        const float4_ hv = *reinterpret_cast<const float4_*>(
            &h_ws[(size_t)(b * N_ + kI[j]) * IND + h * D_ + sub * 4]);
        acc1 += w * hv;
        den1 += w;
    }

    const float den = A * den1 + Bv * den2;
    const float inv = (den > 0.f) ? 1.f / den : 0.f;
    float4_ r = (A * acc1 + Bv * acc2) * inv;
    *reinterpret_cast<float4_*>(&out[(size_t)(b * N_ + q) * IND + h * D_ + sub * 4]) = r;
}

extern "C" void kernel_launch(void* const* d_in, const int* in_sizes, int n_in,
                              void* d_out, int out_size, void* d_ws, size_t ws_size,
                              hipStream_t stream) {
    const float* x     = (const float*)d_in[0];
    const float* alive = (const float*)d_in[1];
    const float* W     = (const float*)d_in[2];
    const float* a_src = (const float*)d_in[3];
    const float* a_dst = (const float*)d_in[4];
    float* out = (float*)d_out;

    float* h_ws   = (float*)d_ws;               // BN*128
    float* sT     = h_ws + (size_t)BN * IND;    // [H][BN]
    float* tT     = sT  + (size_t)H_ * BN;
    float* e1T    = tT  + (size_t)H_ * BN;
    float* e2T    = e1T + (size_t)H_ * BN;
    float* tSg    = e2T + (size_t)H_ * BN;      // [32][N]
    int*   kIg    = (int*)(tSg + 32 * N_);
    float* e1g    = (float*)(kIg + 32 * N_);
    float* e2g    = e1g + 32 * N_;
    float* pre2g  = e2g + 32 * N_;              // 32*65*32
    float* suf1g  = pre2g + 32 * (NCH + 1) * D_;
    float* dpre2g = suf1g + 32 * (NCH + 2) * D_;
    float* dsuf1g = dpre2g + 32 * (NCH + 1);    // total ~5.6 MB

    k_h_alpha<<<BN / RT, 512, 0, stream>>>(x, alive, W, a_src, a_dst,
                                           h_ws, sT, tT, e1T, e2T);

    dim3 g2(N_ / 256, H_, B_);
    k_rank<<<g2, 256, 0, stream>>>(tT, e1T, e2T, tSg, kIg, e1g, e2g);

    dim3 g3(H_, B_);
    k_scan<<<g3, 256, 0, stream>>>(h_ws, kIg, e1g, e2g,
                                   pre2g, suf1g, dpre2g, dsuf1g);

    dim3 g4(N_ / QB, H_, B_);
    k_comb<<<g4, 512, 0, stream>>>(h_ws, sT, tSg, kIg, e1g, e2g,
                                   pre2g, suf1g, dpre2g, dsuf1g, out);
}

// Round 7
// 68.125 us; speedup vs baseline: 2.2126x; 2.2126x over previous
//
#include <hip/hip_runtime.h>
#include <hip/hip_bf16.h>

// GAT layer, B=8 N=1024 IN=128 H=4 D=32. Inputs f32, OUTPUT f32.
//
// k1      : h = x@W^T (W bf16 in LDS, 4 rows/block — round-5 proven version);
//           s/t/e1/e2 per (row,head), transposed [h][bn].
// k_rank  : rank sort by t per (b,h) via brute-force u64-key ranking
//           (key = orderable(t)<<32 | idx -> strict total order, no ties),
//           scatter t/idx/e1/e2 into sorted order in ws.
// k_scan  : per (b,h): chunk sums of e1*h (suffix) / e2*h (prefix) + denoms,
//           WAVE-PARALLEL shuffle scans over 64 chunks, tables -> ws.
// k_comb  : per query: binary search split p (t_k >= -s_q is a sorted suffix),
//           out = (A*suf1[p] + B*pre2[p]) / (A*d1[p] + B*d2[p]) with <=16-key
//           boundary partials per side.

#define B_   8
#define N_   1024
#define BN   (B_ * N_)
#define IND  128
#define H_   4
#define D_   32
#define NEG  0.2f
#define CH   16
#define NCH  (N_ / CH)       // 64
#define QB   64              // queries per k_comb block

typedef float float4_ __attribute__((ext_vector_type(4)));

__device__ __forceinline__ float bf2f(ushort u) {
    union { unsigned int i; float f; } v; v.i = ((unsigned int)u) << 16; return v.f;
}
__device__ __forceinline__ ushort f2bf(float f) {
    union { float f; unsigned int i; } v; v.f = f;
    unsigned int lsb = (v.i >> 16) & 1u;
    v.i += 0x7fffu + lsb;
    return (ushort)(v.i >> 16);
}

// ---------------- Kernel 1: h = x@W^T, alphas, exp factors ----------------
// grid = B*N/4 blocks, 512 threads. Thread t: col c=t&127, row r=t>>7 (of 4).
// (Round-5 version: measured-good. Wl stride 134 ushorts = 67 words, 67%32=3
//  -> LDS banks spread; single accumulator; uint W reads.)
__global__ __launch_bounds__(512) void k_h_alpha(
    const float* __restrict__ x,      // [B*N,128]
    const float* __restrict__ alive,  // [B*N]
    const float* __restrict__ W,      // [128,128]
    const float* __restrict__ a_src,  // [128]
    const float* __restrict__ a_dst,  // [128]
    float* __restrict__ h_ws,         // [B*N,128]
    float* __restrict__ sT,           // [H][BN]
    float* __restrict__ tT,           // [H][BN]
    float* __restrict__ e1T,          // [H][BN]
    float* __restrict__ e2T)          // [H][BN]
{
    __shared__ float  xs[4][IND];
    __shared__ ushort Wl[IND][134];   // bf16 W; 134 ushorts = 67 words (odd)
    __shared__ float  asrc[IND], adst[IND];

    const int t     = threadIdx.x;
    const int rbase = blockIdx.x * 4;
    const int c     = t & 127;
    const int r     = t >> 7;

    xs[r][c] = x[(size_t)(rbase + r) * IND + c];
    if (t < IND) { asrc[t] = a_src[t]; adst[t] = a_dst[t]; }

    const float2* Wf2 = reinterpret_cast<const float2*>(W);
    #pragma unroll
    for (int i = t; i < 8192; i += 512) {
        float2 w2 = Wf2[i];
        unsigned int u = ((unsigned int)f2bf(w2.y) << 16) | (unsigned int)f2bf(w2.x);
        reinterpret_cast<unsigned int*>(Wl[i >> 6])[i & 63] = u;
    }
    __syncthreads();

    const unsigned int* wrow = reinterpret_cast<const unsigned int*>(Wl[c]);
    float acc = 0.f;
    #pragma unroll
    for (int j = 0; j < 64; ++j) {
        unsigned int u = wrow[j];
        acc = fmaf(xs[r][2 * j],     bf2f((ushort)(u & 0xffffu)), acc);
        acc = fmaf(xs[r][2 * j + 1], bf2f((ushort)(u >> 16)),     acc);
    }
    const int row = rbase + r;
    h_ws[(size_t)row * IND + c] = acc;

    float ps = acc * asrc[c];
    float pt = acc * adst[c];
    #pragma unroll
    for (int m = 16; m >= 1; m >>= 1) {
        ps += __shfl_xor(ps, m);
        pt += __shfl_xor(pt, m);
    }
    if ((t & 31) == 0) {
        int idx = (c >> 5) * BN + row;      // transposed [h][bn]
        sT[idx] = ps;
        tT[idx] = pt;
        float am = (alive[row] >= 0.5f) ? 1.f : 0.f;
        e1T[idx] = am * __expf(pt);
        e2T[idx] = am * __expf(NEG * pt);
    }
}

// ---------------- Kernel 2: brute-force u64 rank + scatter ----------------
// grid = (4, H, B), 256 threads. Thread owns key i0 = chunk*256+tid.
__global__ __launch_bounds__(256) void k_rank(
    const float* __restrict__ tT,
    const float* __restrict__ e1T,
    const float* __restrict__ e2T,
    float* __restrict__ tSg,   // [32][N]
    int*   __restrict__ kIg,
    float* __restrict__ e1g,
    float* __restrict__ e2g)
{
    __shared__ unsigned long long keys[N_];   // 8 KB
    const int h = blockIdx.y, b = blockIdx.z;
    const int base = h * BN + b * N_;
    for (int i = threadIdx.x; i < N_; i += 256) {
        unsigned int u = __float_as_uint(tT[base + i]);
        u = (u & 0x80000000u) ? ~u : (u | 0x80000000u);   // orderable transform
        keys[i] = ((unsigned long long)u << 32) | (unsigned int)i;
    }
    __syncthreads();

    const int i0 = blockIdx.x * 256 + threadIdx.x;
    const unsigned long long mk = keys[i0];
    int rank = 0;
    const ulonglong2* k2p = reinterpret_cast<const ulonglong2*>(keys);
    #pragma unroll 8
    for (int j = 0; j < N_ / 2; ++j) {
        ulonglong2 kk = k2p[j];
        rank += (int)(kk.x < mk) + (int)(kk.y < mk);
    }
    const int o = (b * H_ + h) * N_ + rank;
    tSg[o] = tT[base + i0];
    kIg[o] = i0;
    e1g[o] = e1T[base + i0];
    e2g[o] = e2T[base + i0];
}

// ---------------- Kernel 3: chunk sums + wave-parallel scans --------------
// grid = (H, B), 256 threads.
__global__ __launch_bounds__(256) void k_scan(
    const float* __restrict__ h_ws,
    const int*   __restrict__ kIg,
    const float* __restrict__ e1g,
    const float* __restrict__ e2g,
    float* __restrict__ pre2g,   // [32][65][32]
    float* __restrict__ suf1g,   // [32][66][32]
    float* __restrict__ dpre2g,  // [32][65]
    float* __restrict__ dsuf1g)  // [32][66]
{
    __shared__ int   kI[N_];
    __shared__ float e1S[N_], e2S[N_];
    __shared__ float pre2[NCH + 1][33];   // pad 33: scan reads hit distinct banks
    __shared__ float suf1[NCH + 2][33];
    __shared__ float dpre2[NCH + 1], dsuf1[NCH + 2];

    const int h = blockIdx.x, b = blockIdx.y;
    const int bhi = b * H_ + h;
    const int so  = bhi * N_;
    const int tid = threadIdx.x;

    for (int i = tid; i < N_; i += 256) {
        kI[i]  = kIg[so + i];
        e1S[i] = e1g[so + i];
        e2S[i] = e2g[so + i];
    }
    __syncthreads();

    // chunk sums; (cc, dim-group) cells; 8 dg lanes share each key row -> coalesced
    for (int c4 = tid; c4 < NCH * 8; c4 += 256) {
        int cc = c4 >> 3, dg = c4 & 7;
        float4_ a1 = {0.f, 0.f, 0.f, 0.f}, a2 = {0.f, 0.f, 0.f, 0.f};
        #pragma unroll
        for (int jj = 0; jj < CH; ++jj) {
            int j = cc * CH + jj;
            const float4_ hv = *reinterpret_cast<const float4_*>(
                &h_ws[(size_t)(b * N_ + kI[j]) * IND + h * D_ + dg * 4]);
            a1 += e1S[j] * hv;
            a2 += e2S[j] * hv;
        }
        #pragma unroll
        for (int u = 0; u < 4; ++u) {
            pre2[cc + 1][dg * 4 + u] = a2[u];
            suf1[cc][dg * 4 + u]     = a1[u];
        }
    }
    if (tid < NCH) {
        float s = 0.f;
        #pragma unroll
        for (int jj = 0; jj < CH; ++jj) s += e2S[tid * CH + jj];
        dpre2[tid + 1] = s;
    } else if (tid < 2 * NCH) {
        int cc = tid - NCH;
        float s = 0.f;
        #pragma unroll
        for (int jj = 0; jj < CH; ++jj) s += e1S[cc * CH + jj];
        dsuf1[cc] = s;
    }
    __syncthreads();

    // wave-parallel scans: wave wv handles dims wv, wv+4, ... (64 chunks = 64 lanes)
    const int wv = tid >> 6, lane = tid & 63;
    for (int d = wv; d < D_; d += 4) {
        float v = pre2[lane + 1][d];
        #pragma unroll
        for (int off = 1; off < 64; off <<= 1) {
            float n = __shfl_up(v, off);
            if (lane >= off) v += n;
        }
        pre2[lane + 1][d] = v;
        if (lane == 0) pre2[0][d] = 0.f;
    }
    for (int d = wv; d < D_; d += 4) {
        float v = suf1[lane][d];
        #pragma unroll
        for (int off = 1; off < 64; off <<= 1) {
            float n = __shfl_down(v, off);
            if (lane < 64 - off) v += n;
        }
        suf1[lane][d] = v;
        if (lane == 0) { suf1[NCH][d] = 0.f; suf1[NCH + 1][d] = 0.f; }
    }
    if (tid < 64) {
        float v = dpre2[lane + 1];
        #pragma unroll
        for (int off = 1; off < 64; off <<= 1) {
            float n = __shfl_up(v, off);
            if (lane >= off) v += n;
        }
        dpre2[lane + 1] = v;
        if (lane == 0) dpre2[0] = 0.f;
    } else if (tid < 128) {
        float v = dsuf1[lane];
        #pragma unroll
        for (int off = 1; off < 64; off <<= 1) {
            float n = __shfl_down(v, off);
            if (lane < 64 - off) v += n;
        }
        dsuf1[lane] = v;
        if (lane == 0) { dsuf1[NCH] = 0.f; dsuf1[NCH + 1] = 0.f; }
    }
    __syncthreads();

    for (int i = tid; i < (NCH + 1) * D_; i += 256)
        pre2g[bhi * (NCH + 1) * D_ + i] = pre2[i >> 5][i & 31];
    for (int i = tid; i < (NCH + 2) * D_; i += 256)
        suf1g[bhi * (NCH + 2) * D_ + i] = suf1[i >> 5][i & 31];
    if (tid < NCH + 1) dpre2g[bhi * (NCH + 1) + tid] = dpre2[tid];
    else if (tid < (NCH + 1) + (NCH + 2)) {
        int i = tid - (NCH + 1);
        dsuf1g[bhi * (NCH + 2) + i] = dsuf1[i];
    }
}

// ---------------- Kernel 4: per-query combine -----------------------------
// grid = (N/QB, H, B), 512 threads: 64 queries x 8 dim-groups.
__global__ __launch_bounds__(512) void k_comb(
    const float* __restrict__ h_ws,
    const float* __restrict__ sT,
    const float* __restrict__ tSg,
    const int*   __restrict__ kIg,
    const float* __restrict__ e1g,
    const float* __restrict__ e2g,
    const float* __restrict__ pre2g,
    const float* __restrict__ suf1g,
    const float* __restrict__ dpre2g,
    const float* __restrict__ dsuf1g,
    float* __restrict__ out)
{
    __shared__ float tS[N_];
    __shared__ int   kI[N_];
    __shared__ float e1S[N_], e2S[N_];
    __shared__ float pre2[NCH + 1][36];   // stride 36: float4-aligned + bank spread
    __shared__ float suf1[NCH + 2][36];
    __shared__ float dpre2[NCH + 1], dsuf1[NCH + 2];

    const int h = blockIdx.y, b = blockIdx.z, qb = blockIdx.x;
    const int bhi = b * H_ + h;
    const int so  = bhi * N_;
    const int tid = threadIdx.x;

    for (int i = tid; i < N_; i += 512) {
        tS[i]  = tSg[so + i];
        kI[i]  = kIg[so + i];
        e1S[i] = e1g[so + i];
        e2S[i] = e2g[so + i];
    }
    for (int i = tid; i < (NCH + 1) * D_; i += 512)
        pre2[i >> 5][i & 31] = pre2g[bhi * (NCH + 1) * D_ + i];
    for (int i = tid; i < (NCH + 2) * D_; i += 512)
        suf1[i >> 5][i & 31] = suf1g[bhi * (NCH + 2) * D_ + i];
    if (tid < NCH + 1) dpre2[tid] = dpre2g[bhi * (NCH + 1) + tid];
    else if (tid < (NCH + 1) + (NCH + 2)) {
        int i = tid - (NCH + 1);
        dsuf1[i] = dsuf1g[bhi * (NCH + 2) + i];
    }
    __syncthreads();

    const int ql  = tid >> 3;         // 0..63
    const int sub = tid & 7;          // dim group
    const int q   = qb * QB + ql;

    const float s  = sT[h * BN + b * N_ + q];
    const float A  = __expf(s);
    const float Bv = __expf(NEG * s);
    const float tau = -s;
    int lo = 0, hi = N_;
    #pragma unroll
    for (int it = 0; it < 10; ++it) {
        int mid = (lo + hi) >> 1;
        if (tS[mid] >= tau) hi = mid; else lo = mid + 1;
    }
    const int p  = lo;
    const int cp = p >> 4;

    float4_ acc2 = *reinterpret_cast<const float4_*>(&pre2[cp][sub * 4]);
    float   den2 = dpre2[cp];
    for (int j = cp << 4; j < p; ++j) {
        float w = e2S[j];
        const float4_ hv = *reinterpret_cast<const float4_*>(
            &h_ws[(size_t)(b * N_ + kI[j]) * IND + h * D_ + sub * 4]);
        acc2 += w * hv;
        den2 += w;
    }
    float4_ acc1 = *reinterpret_cast<const float4_*>(&suf1[cp + 1][sub * 4]);
    float   den1 = dsuf1[cp + 1];
    const int je = min((cp << 4) + CH, N_);
    for (int j = p; j < je; ++j) {
        float w = e1S[j];
        const float4_ hv = *reinterpret_cast<const float4_*>(
            &h_ws[(size_t)(b * N_ + kI[j]) * IND + h * D_ + sub * 4]);
        acc1 += w * hv;
        den1 += w;
    }

    const float den = A * den1 + Bv * den2;
    const float inv = (den > 0.f) ? 1.f / den : 0.f;
    float4_ r = (A * acc1 + Bv * acc2) * inv;
    *reinterpret_cast<float4_*>(&out[(size_t)(b * N_ + q) * IND + h * D_ + sub * 4]) = r;
}

extern "C" void kernel_launch(void* const* d_in, const int* in_sizes, int n_in,
                              void* d_out, int out_size, void* d_ws, size_t ws_size,
                              hipStream_t stream) {
    const float* x     = (const float*)d_in[0];
    const float* alive = (const float*)d_in[1];
    const float* W     = (const float*)d_in[2];
    const float* a_src = (const float*)d_in[3];
    const float* a_dst = (const float*)d_in[4];
    float* out = (float*)d_out;

    float* h_ws   = (float*)d_ws;               // BN*128
    float* sT     = h_ws + (size_t)BN * IND;    // [H][BN]
    float* tT     = sT  + (size_t)H_ * BN;
    float* e1T    = tT  + (size_t)H_ * BN;
    float* e2T    = e1T + (size_t)H_ * BN;
    float* tSg    = e2T + (size_t)H_ * BN;      // [32][N]
    int*   kIg    = (int*)(tSg + 32 * N_);
    float* e1g    = (float*)(kIg + 32 * N_);
    float* e2g    = e1g + 32 * N_;
    float* pre2g  = e2g + 32 * N_;              // 32*65*32
    float* suf1g  = pre2g + 32 * (NCH + 1) * D_;
    float* dpre2g = suf1g + 32 * (NCH + 2) * D_;
    float* dsuf1g = dpre2g + 32 * (NCH + 1);    // total ~5.6 MB

    k_h_alpha<<<BN / 4, 512, 0, stream>>>(x, alive, W, a_src, a_dst,
                                          h_ws, sT, tT, e1T, e2T);

    dim3 g2(N_ / 256, H_, B_);
    k_rank<<<g2, 256, 0, stream>>>(tT, e1T, e2T, tSg, kIg, e1g, e2g);

    dim3 g3(H_, B_);
    k_scan<<<g3, 256, 0, stream>>>(h_ws, kIg, e1g, e2g,
                                   pre2g, suf1g, dpre2g, dsuf1g);

    dim3 g4(N_ / QB, H_, B_);
    k_comb<<<g4, 512, 0, stream>>>(h_ws, sT, tSg, kIg, e1g, e2g,
                                   pre2g, suf1g, dpre2g, dsuf1g, out);
}

// Round 8
// 51.101 us; speedup vs baseline: 2.9497x; 1.3331x over previous
//
#include <hip/hip_runtime.h>
#include <hip/hip_bf16.h>

// GAT layer, B=8 N=1024 IN=128 H=4 D=32. Inputs f32, OUTPUT f32.
//
// kA (k_gemm_alpha): h = x@W^T via MFMA 16x16x32 bf16 (x split hi+lo bf16 ->
//     ~f32 x precision; W single bf16 = proven rounding). Fused epilogue:
//     s/t/e1/e2 per (row,head) written transposed [h][bn].
// k_rank : brute-force u64-key rank sort by t per (b,h), scatter to ws.
// k_sums : raw per-chunk sums of e1*h (suffix side) / e2*h (prefix side) +
//          chunk denominators. grid (H,B,4) for parallelism; NO scan phase.
// k_comb : stages chunk sums, does the 64-lane shuffle scan in-block, then
//          per query: binary search split p, combine tables + <=16-key
//          boundary partials per side.

#define B_   8
#define N_   1024
#define BN   (B_ * N_)
#define IND  128
#define H_   4
#define D_   32
#define NEG  0.2f
#define CH   16
#define NCH  (N_ / CH)       // 64
#define QB   64              // queries per k_comb block

typedef float float4_ __attribute__((ext_vector_type(4)));
typedef short short8_ __attribute__((ext_vector_type(8)));

__device__ __forceinline__ float bf2f(ushort u) {
    union { unsigned int i; float f; } v; v.i = ((unsigned int)u) << 16; return v.f;
}
__device__ __forceinline__ ushort f2bf(float f) {
    union { float f; unsigned int i; } v; v.f = f;
    unsigned int lsb = (v.i >> 16) & 1u;
    v.i += 0x7fffu + lsb;
    return (ushort)(v.i >> 16);
}
__device__ __forceinline__ short8_ pack_hi(float4_ a, float4_ b) {
    short8_ r;
    r[0] = (short)f2bf(a[0]); r[1] = (short)f2bf(a[1]);
    r[2] = (short)f2bf(a[2]); r[3] = (short)f2bf(a[3]);
    r[4] = (short)f2bf(b[0]); r[5] = (short)f2bf(b[1]);
    r[6] = (short)f2bf(b[2]); r[7] = (short)f2bf(b[3]);
    return r;
}
__device__ __forceinline__ void split_bf(float4_ a, float4_ b, short8_& hi, short8_& lo) {
    #pragma unroll
    for (int j = 0; j < 4; ++j) {
        ushort h0 = f2bf(a[j]); hi[j]     = (short)h0; lo[j]     = (short)f2bf(a[j] - bf2f(h0));
        ushort h1 = f2bf(b[j]); hi[j + 4] = (short)h1; lo[j + 4] = (short)f2bf(b[j] - bf2f(h1));
    }
}

// ---------------- Kernel A: MFMA GEMM + alpha epilogue --------------------
// grid = 256 blocks x 256 thr (4 waves). Block: 32 rows (2 M-tiles of 16).
// Wave wv owns n-tiles {2wv, 2wv+1} (16 cols each) -> 128 cols.
// Frag maps (16x16x32): A row=lane&15, k=(lane>>4)*8+j (8 contig f32 in x row)
//                       B col=lane&15 (W row n), same k (8 contig in W row)
//                       D col=lane&15, row=(lane>>4)*4+reg  [m89-verified]
__global__ __launch_bounds__(256) void k_gemm_alpha(
    const float* __restrict__ x,      // [B*N,128]
    const float* __restrict__ alive,  // [B*N]
    const float* __restrict__ W,      // [128,128]
    const float* __restrict__ a_src,  // [128]
    const float* __restrict__ a_dst,  // [128]
    float* __restrict__ h_ws,         // [B*N,128]
    float* __restrict__ sT,           // [H][BN]
    float* __restrict__ tT,           // [H][BN]
    float* __restrict__ e1T,          // [H][BN]
    float* __restrict__ e2T)          // [H][BN]
{
    __shared__ float hs[32][132];     // 16.9 KB (132: 528B rows, 16B-aligned)
    __shared__ float asrc[IND], adst[IND];

    const int tid = threadIdx.x;
    const int wv  = tid >> 6;         // 0..3
    const int ln  = tid & 63;
    const int l15 = ln & 15;
    const int lg  = ln >> 4;          // k-group 0..3
    const int rbase = blockIdx.x * 32;

    if (tid < IND) { asrc[tid] = a_src[tid]; adst[tid] = a_dst[tid]; }

    // B-frags from global W (bf16-rounded; 8 frags, kept in regs)
    short8_ bf[2][4];
    #pragma unroll
    for (int t = 0; t < 2; ++t) {
        const float* wr = &W[(size_t)((wv * 2 + t) * 16 + l15) * IND + lg * 8];
        #pragma unroll
        for (int ks = 0; ks < 4; ++ks) {
            float4_ v0 = *reinterpret_cast<const float4_*>(wr + ks * 32);
            float4_ v1 = *reinterpret_cast<const float4_*>(wr + ks * 32 + 4);
            bf[t][ks] = pack_hi(v0, v1);
        }
    }

    float4_ acc[2][2];
    #pragma unroll
    for (int mt = 0; mt < 2; ++mt) {
        const float* xr = &x[(size_t)(rbase + mt * 16 + l15) * IND + lg * 8];
        short8_ ahi[4], alo[4];
        #pragma unroll
        for (int ks = 0; ks < 4; ++ks) {
            float4_ v0 = *reinterpret_cast<const float4_*>(xr + ks * 32);
            float4_ v1 = *reinterpret_cast<const float4_*>(xr + ks * 32 + 4);
            split_bf(v0, v1, ahi[ks], alo[ks]);
        }
        #pragma unroll
        for (int t = 0; t < 2; ++t) {
            float4_ a = {0.f, 0.f, 0.f, 0.f};
            #pragma unroll
            for (int ks = 0; ks < 4; ++ks) {
                a = __builtin_amdgcn_mfma_f32_16x16x32_bf16(ahi[ks], bf[t][ks], a, 0, 0, 0);
                a = __builtin_amdgcn_mfma_f32_16x16x32_bf16(alo[ks], bf[t][ks], a, 0, 0, 0);
            }
            acc[mt][t] = a;
        }
    }

    // D frags -> hs
    #pragma unroll
    for (int mt = 0; mt < 2; ++mt)
        #pragma unroll
        for (int t = 0; t < 2; ++t) {
            const int col = (wv * 2 + t) * 16 + l15;
            #pragma unroll
            for (int r = 0; r < 4; ++r)
                hs[mt * 16 + lg * 4 + r][col] = acc[mt][t][r];
        }
    __syncthreads();

    // h -> global, coalesced float4
    #pragma unroll
    for (int i = tid; i < 1024; i += 256) {
        int row = i >> 5, c4 = (i & 31) * 4;
        *reinterpret_cast<float4_*>(&h_ws[(size_t)(rbase + row) * IND + c4]) =
            *reinterpret_cast<const float4_*>(&hs[row][c4]);
    }

    // s,t,e1,e2 per (row,head)
    if (tid < 128) {
        const int row = tid >> 2, hh = tid & 3;
        const float* hr = &hs[row][hh * 32];
        float s = 0.f, tt = 0.f;
        #pragma unroll
        for (int d = 0; d < 32; ++d) {
            s  = fmaf(hr[d], asrc[hh * 32 + d], s);
            tt = fmaf(hr[d], adst[hh * 32 + d], tt);
        }
        const int grow = rbase + row;
        const int idx  = hh * BN + grow;
        sT[idx] = s;
        tT[idx] = tt;
        float am = (alive[grow] >= 0.5f) ? 1.f : 0.f;
        e1T[idx] = am * __expf(tt);
        e2T[idx] = am * __expf(NEG * tt);
    }
}

// ---------------- Kernel 2: brute-force u64 rank + scatter ----------------
// grid = (4, H, B), 256 threads. Thread owns key i0 = chunk*256+tid.
__global__ __launch_bounds__(256) void k_rank(
    const float* __restrict__ tT,
    const float* __restrict__ e1T,
    const float* __restrict__ e2T,
    float* __restrict__ tSg,   // [32][N]
    int*   __restrict__ kIg,
    float* __restrict__ e1g,
    float* __restrict__ e2g)
{
    __shared__ unsigned long long keys[N_];   // 8 KB
    const int h = blockIdx.y, b = blockIdx.z;
    const int base = h * BN + b * N_;
    for (int i = threadIdx.x; i < N_; i += 256) {
        unsigned int u = __float_as_uint(tT[base + i]);
        u = (u & 0x80000000u) ? ~u : (u | 0x80000000u);   // orderable transform
        keys[i] = ((unsigned long long)u << 32) | (unsigned int)i;
    }
    __syncthreads();

    const int i0 = blockIdx.x * 256 + threadIdx.x;
    const unsigned long long mk = keys[i0];
    int rank = 0;
    const ulonglong2* k2p = reinterpret_cast<const ulonglong2*>(keys);
    #pragma unroll 8
    for (int j = 0; j < N_ / 2; ++j) {
        ulonglong2 kk = k2p[j];
        rank += (int)(kk.x < mk) + (int)(kk.y < mk);
    }
    const int o = (b * H_ + h) * N_ + rank;
    tSg[o] = tT[base + i0];
    kIg[o] = i0;
    e1g[o] = e1T[base + i0];
    e2g[o] = e2T[base + i0];
}

// ---------------- Kernel 3: raw chunk sums (no scan) ----------------------
// grid = (H, B, 4), 256 threads. Block covers 16 chunks (256 sorted keys).
// thread -> (half=tid&1, dg=(tid>>1)&7, cc=tid>>4); pair-combine via shfl.
__global__ __launch_bounds__(256) void k_sums(
    const float* __restrict__ h_ws,
    const int*   __restrict__ kIg,
    const float* __restrict__ e1g,
    const float* __restrict__ e2g,
    float* __restrict__ pre2r,   // [32][64][32] raw e2-weighted chunk sums
    float* __restrict__ suf1r,   // [32][64][32] raw e1-weighted chunk sums
    float* __restrict__ dpre2r,  // [32][64]
    float* __restrict__ dsuf1r)  // [32][64]
{
    __shared__ int   kI[256];
    __shared__ float e1S[256], e2S[256];

    const int h = blockIdx.x, b = blockIdx.y, cz = blockIdx.z;
    const int bhi = b * H_ + h;
    const int so  = bhi * N_ + cz * 256;
    const int tid = threadIdx.x;

    kI[tid]  = kIg[so + tid];
    e1S[tid] = e1g[so + tid];
    e2S[tid] = e2g[so + tid];
    __syncthreads();

    const int half = tid & 1, dg = (tid >> 1) & 7, cc = tid >> 4;
    float4_ a1 = {0.f, 0.f, 0.f, 0.f}, a2 = {0.f, 0.f, 0.f, 0.f};
    float d1 = 0.f, d2 = 0.f;
    #pragma unroll
    for (int jj = 0; jj < 8; ++jj) {
        const int j = cc * CH + half * 8 + jj;
        const float4_ hv = *reinterpret_cast<const float4_*>(
            &h_ws[(size_t)(b * N_ + kI[j]) * IND + h * D_ + dg * 4]);
        a1 += e1S[j] * hv;
        a2 += e2S[j] * hv;
        d1 += e1S[j];
        d2 += e2S[j];
    }
    #pragma unroll
    for (int u = 0; u < 4; ++u) {
        a1[u] += __shfl_xor(a1[u], 1);
        a2[u] += __shfl_xor(a2[u], 1);
    }
    d1 += __shfl_xor(d1, 1);
    d2 += __shfl_xor(d2, 1);

    if (!half) {
        const int gcc = cz * 16 + cc;
        *reinterpret_cast<float4_*>(&pre2r[(bhi * NCH + gcc) * D_ + dg * 4]) = a2;
        *reinterpret_cast<float4_*>(&suf1r[(bhi * NCH + gcc) * D_ + dg * 4]) = a1;
        if (dg == 0) {
            dpre2r[bhi * NCH + gcc] = d2;
            dsuf1r[bhi * NCH + gcc] = d1;
        }
    }
}

// ---------------- Kernel 4: scan-in-staging + per-query combine -----------
// grid = (N/QB, H, B), 512 threads: 64 queries x 8 dim-groups.
__global__ __launch_bounds__(512) void k_comb(
    const float* __restrict__ h_ws,
    const float* __restrict__ sT,
    const float* __restrict__ tSg,
    const int*   __restrict__ kIg,
    const float* __restrict__ e1g,
    const float* __restrict__ e2g,
    const float* __restrict__ pre2r,
    const float* __restrict__ suf1r,
    const float* __restrict__ dpre2r,
    const float* __restrict__ dsuf1r,
    float* __restrict__ out)
{
    __shared__ float tS[N_];
    __shared__ int   kI[N_];
    __shared__ float e1S[N_], e2S[N_];
    __shared__ float pre2[NCH + 1][36];   // stride 36: float4-aligned + bank spread
    __shared__ float suf1[NCH + 2][36];
    __shared__ float dpre2[NCH + 1], dsuf1[NCH + 2];

    const int h = blockIdx.y, b = blockIdx.z, qb = blockIdx.x;
    const int bhi = b * H_ + h;
    const int so  = bhi * N_;
    const int tid = threadIdx.x;

    for (int i = tid; i < N_; i += 512) {
        tS[i]  = tSg[so + i];
        kI[i]  = kIg[so + i];
        e1S[i] = e1g[so + i];
        e2S[i] = e2g[so + i];
    }
    for (int i = tid; i < NCH * D_; i += 512) {
        const int cc = i >> 5, d = i & 31;
        pre2[cc + 1][d] = pre2r[bhi * NCH * D_ + i];
        suf1[cc][d]     = suf1r[bhi * NCH * D_ + i];
    }
    if (tid < NCH) dpre2[tid + 1] = dpre2r[bhi * NCH + tid];
    else if (tid < 2 * NCH) dsuf1[tid - NCH] = dsuf1r[bhi * NCH + (tid - NCH)];
    __syncthreads();

    // in-block scans: waves 0-3 prefix (pre2 dims), waves 4-7 suffix (suf1)
    {
        const int wv = tid >> 6, lane = tid & 63;
        if (wv < 4) {
            for (int d = wv; d < D_; d += 4) {
                float v = pre2[lane + 1][d];
                #pragma unroll
                for (int off = 1; off < 64; off <<= 1) {
                    float n = __shfl_up(v, off);
                    if (lane >= off) v += n;
                }
                pre2[lane + 1][d] = v;
                if (lane == 0) pre2[0][d] = 0.f;
            }
            if (wv == 0) {
                float v = dpre2[lane + 1];
                #pragma unroll
                for (int off = 1; off < 64; off <<= 1) {
                    float n = __shfl_up(v, off);
                    if (lane >= off) v += n;
                }
                dpre2[lane + 1] = v;
                if (lane == 0) dpre2[0] = 0.f;
            }
        } else {
            for (int d = wv - 4; d < D_; d += 4) {
                float v = suf1[lane][d];
                #pragma unroll
                for (int off = 1; off < 64; off <<= 1) {
                    float n = __shfl_down(v, off);
                    if (lane < 64 - off) v += n;
                }
                suf1[lane][d] = v;
                if (lane == 0) { suf1[NCH][d] = 0.f; suf1[NCH + 1][d] = 0.f; }
            }
            if (wv == 4) {
                float v = dsuf1[lane];
                #pragma unroll
                for (int off = 1; off < 64; off <<= 1) {
                    float n = __shfl_down(v, off);
                    if (lane < 64 - off) v += n;
                }
                dsuf1[lane] = v;
                if (lane == 0) { dsuf1[NCH] = 0.f; dsuf1[NCH + 1] = 0.f; }
            }
        }
    }
    __syncthreads();

    const int ql  = tid >> 3;         // 0..63
    const int sub = tid & 7;          // dim group
    const int q   = qb * QB + ql;

    const float s  = sT[h * BN + b * N_ + q];
    const float A  = __expf(s);
    const float Bv = __expf(NEG * s);
    const float tau = -s;
    int lo = 0, hi = N_;
    #pragma unroll
    for (int it = 0; it < 10; ++it) {
        int mid = (lo + hi) >> 1;
        if (tS[mid] >= tau) hi = mid; else lo = mid + 1;
    }
    const int p  = lo;
    const int cp = p >> 4;

    float4_ acc2 = *reinterpret_cast<const float4_*>(&pre2[cp][sub * 4]);
    float   den2 = dpre2[cp];
    for (int j = cp << 4; j < p; ++j) {
        float w = e2S[j];
        const float4_ hv = *reinterpret_cast<const float4_*>(
            &h_ws[(size_t)(b * N_ + kI[j]) * IND + h * D_ + sub * 4]);
        acc2 += w * hv;
        den2 += w;
    }
    float4_ acc1 = *reinterpret_cast<const float4_*>(&suf1[cp + 1][sub * 4]);
    float   den1 = dsuf1[cp + 1];
    const int je = min((cp << 4) + CH, N_);
    for (int j = p; j < je; ++j) {
        float w = e1S[j];
        const float4_ hv = *reinterpret_cast<const float4_*>(
            &h_ws[(size_t)(b * N_ + kI[j]) * IND + h * D_ + sub * 4]);
        acc1 += w * hv;
        den1 += w;
    }

    const float den = A * den1 + Bv * den2;
    const float inv = (den > 0.f) ? 1.f / den : 0.f;
    float4_ r = (A * acc1 + Bv * acc2) * inv;
    *reinterpret_cast<float4_*>(&out[(size_t)(b * N_ + q) * IND + h * D_ + sub * 4]) = r;
}

extern "C" void kernel_launch(void* const* d_in, const int* in_sizes, int n_in,
                              void* d_out, int out_size, void* d_ws, size_t ws_size,
                              hipStream_t stream) {
    const float* x     = (const float*)d_in[0];
    const float* alive = (const float*)d_in[1];
    const float* W     = (const float*)d_in[2];
    const float* a_src = (const float*)d_in[3];
    const float* a_dst = (const float*)d_in[4];
    float* out = (float*)d_out;

    float* h_ws   = (float*)d_ws;               // BN*128
    float* sT     = h_ws + (size_t)BN * IND;    // [H][BN]
    float* tT     = sT  + (size_t)H_ * BN;
    float* e1T    = tT  + (size_t)H_ * BN;
    float* e2T    = e1T + (size_t)H_ * BN;
    float* tSg    = e2T + (size_t)H_ * BN;      // [32][N]
    int*   kIg    = (int*)(tSg + 32 * N_);
    float* e1g    = (float*)(kIg + 32 * N_);
    float* e2g    = e1g + 32 * N_;
    float* pre2r  = e2g + 32 * N_;              // [32][64][32]
    float* suf1r  = pre2r + 32 * NCH * D_;
    float* dpre2r = suf1r + 32 * NCH * D_;      // [32][64]
    float* dsuf1r = dpre2r + 32 * NCH;          // total ~5.8 MB

    k_gemm_alpha<<<BN / 32, 256, 0, stream>>>(x, alive, W, a_src, a_dst,
                                              h_ws, sT, tT, e1T, e2T);

    dim3 g2(N_ / 256, H_, B_);
    k_rank<<<g2, 256, 0, stream>>>(tT, e1T, e2T, tSg, kIg, e1g, e2g);

    dim3 g3(H_, B_, 4);
    k_sums<<<g3, 256, 0, stream>>>(h_ws, kIg, e1g, e2g,
                                   pre2r, suf1r, dpre2r, dsuf1r);

    dim3 g4(N_ / QB, H_, B_);
    k_comb<<<g4, 512, 0, stream>>>(h_ws, sT, tSg, kIg, e1g, e2g,
                                   pre2r, suf1r, dpre2r, dsuf1r, out);
}